// Round 8
// baseline (18556.258 us; speedup 1.0000x reference)
//
#include <hip/hip_runtime.h>
#include <stdint.h>

// ---------------------------------------------------------------------------
// RNN speech decoder. R12:
//  * R8-R11 lesson: ANY cross-block h-exchange costs a device-scope L3
//    round trip per step (~5-8k cy) regardless of protocol. R12 removes the
//    exchange: one 1024-thread block owns one (dir, chunk) with the FULL
//    Wh (512x1536) resident as packed-f16 pairs in 384 VGPRs/thread
//    (4 waves/SIMD, cap 512 via __launch_bounds__(1024,4)). h lives in
//    2KB LDS (f16). Dot = v_dot2_f32_f16 (fallback: unpack+fma).
//    CLEN=32/WARM=64 -> 96 steps, 128 independent blocks. No sync, no
//    residency constraints, no deadlock surface.
//  * Thread map: c = tid>>1 (h column), half = tid&1 (row half). Even
//    thread computes the full GRU tail for its column (r,z,n are its 3
//    weight cols) after one shfl_xor(1) partial-sum merge.
//  * GEMM stack / decoder / day path unchanged (R5 lineage, proven).
// ---------------------------------------------------------------------------

#define T_SEQ 2048
#define G3    1536
#define GS    3072   // fused gate width (fwd | bwd)
#define HW    256    // packed bf16 words per h vector
#define CLEN  32
#define WARM  64
#define NSTP  96     // CLEN+WARM

typedef __attribute__((ext_vector_type(8))) short short8;
typedef __attribute__((ext_vector_type(4))) float f32x4;
typedef _Float16 f16x2 __attribute__((ext_vector_type(2)));

__device__ inline unsigned int pack_bf16(float a, float b){
  unsigned int ua = __float_as_uint(a); ua = (ua + 0x7FFFu + ((ua>>16)&1u)) >> 16;
  unsigned int ub = __float_as_uint(b); ub = (ub + 0x7FFFu + ((ub>>16)&1u)) >> 16;
  return (ub<<16) | (ua & 0xFFFFu);
}
__device__ inline float bf2f(unsigned int h){ return __uint_as_float(h<<16); }

__device__ inline f16x2 u2h(unsigned int u){ return __builtin_bit_cast(f16x2, u); }

#if defined(__has_builtin)
#if __has_builtin(__builtin_amdgcn_fdot2)
#define HAS_FDOT2 1
#endif
#endif
__device__ inline float fdot2f(unsigned int w, unsigned int h, float acc){
#ifdef HAS_FDOT2
  return __builtin_amdgcn_fdot2(u2h(w), u2h(h), acc, false);
#else
  f16x2 a = u2h(w), b = u2h(h);
  return acc + (float)a.x*(float)b.x + (float)a.y*(float)b.y;
#endif
}

#define GBN 128
#define GBK 64
#define LSTR 36

// ---------------------------------------------------------------------------
// Day GEMM: C = softsign(x @ dayWT + bsel) -> bf16 hpadb rows 31..8222.
// ---------------------------------------------------------------------------
__global__ __launch_bounds__(256)
void day_gemm(const float* __restrict__ A, const unsigned int* __restrict__ Bpk,
              const float* __restrict__ bias, unsigned short* __restrict__ Cb)
{
  __shared__ __align__(16) unsigned int aL[128*LSTR];
  __shared__ __align__(16) unsigned int bL[GBN*LSTR];
  const int tid = threadIdx.x;
  const int m0 = blockIdx.x * 128;
  const int n0 = blockIdx.y * GBN;
  const int lane = tid & 63;
  const int w = tid >> 6;
  const int wm = (w & 1) * 64;
  const int wn = (w >> 1) * 64;
  const int ln = lane & 15;
  const int q  = lane >> 4;
  const int K = 512;

  f32x4 acc[4][4];
#pragma unroll
  for (int i=0;i<4;i++)
#pragma unroll
    for (int j=0;j<4;j++) acc[i][j] = (f32x4)0.f;

  const int ar = tid >> 1, ah = tid & 1;
  const int br = tid >> 1, bh = tid & 1;

  for (int kt = 0; kt < K/GBK; kt++){
    {
      const float* ap = A + (size_t)(m0+ar)*K + kt*GBK + ah*32;
      float4 av[8];
#pragma unroll
      for (int g=0; g<8; g++) av[g] = ((const float4*)ap)[g];
#pragma unroll
      for (int g=0; g<8; g++){
        aL[ar*LSTR + ah*16 + g*2    ] = pack_bf16(av[g].x, av[g].y);
        aL[ar*LSTR + ah*16 + g*2 + 1] = pack_bf16(av[g].z, av[g].w);
      }
    }
    {
      const unsigned int* bp = Bpk + (size_t)(n0+br)*(K>>1) + kt*32 + bh*16;
#pragma unroll
      for (int g=0; g<4; g++)
        *((uint4*)&bL[br*LSTR + bh*16 + g*4]) = ((const uint4*)bp)[g];
    }
    __syncthreads();
#pragma unroll
    for (int ks=0; ks<2; ks++){
      short8 af[4], bf[4];
#pragma unroll
      for (int i=0;i<4;i++){
        uint4 u = *(const uint4*)&aL[(wm + i*16 + ln)*LSTR + ks*16 + q*4];
        af[i] = *(const short8*)&u;
      }
#pragma unroll
      for (int j=0;j<4;j++){
        uint4 u = *(const uint4*)&bL[(wn + j*16 + ln)*LSTR + ks*16 + q*4];
        bf[j] = *(const short8*)&u;
      }
#pragma unroll
      for (int i=0;i<4;i++)
#pragma unroll
        for (int j=0;j<4;j++)
          acc[i][j] = __builtin_amdgcn_mfma_f32_16x16x32_bf16(af[i], bf[j], acc[i][j], 0,0,0);
    }
    __syncthreads();
  }
#pragma unroll
  for (int i=0;i<4;i++)
#pragma unroll
    for (int j=0;j<4;j++){
      int n = n0 + wn + j*16 + ln;
      float bs = bias[n];
#pragma unroll
      for (int r=0;r<4;r++){
        int m = m0 + wm + i*16 + q*4 + r;
        float v = acc[i][j][r] + bs;
        v = v / (1.f + fabsf(v));
        Cb[(size_t)(m+31)*512 + n] = (unsigned short)(pack_bf16(v, v) & 0xFFFFu);
      }
    }
}

// ---------------------------------------------------------------------------
// Input-gate GEMM, bf16 A (unchanged).
// ---------------------------------------------------------------------------
template<int BM, int AM>
__global__ __launch_bounds__(256)
void gemm_bt(const unsigned short* __restrict__ Abf,
             const unsigned int* __restrict__ A1, const unsigned int* __restrict__ A2,
             const unsigned int* __restrict__ Bpk,
             const float* __restrict__ biasF, const float* __restrict__ biasB,
             float* __restrict__ C, int K, int ldc)
{
  constexpr int AI = BM/32;
  __shared__ __align__(16) unsigned int aL[BM*LSTR];
  __shared__ __align__(16) unsigned int bL[GBN*LSTR];
  const int tid = threadIdx.x;
  const int m0 = blockIdx.x * BM;
  const int n0 = blockIdx.y * GBN;
  const int lane = tid & 63;
  const int w = tid >> 6;
  const int wm = (w & 1) * (BM/2);
  const int wn = (w >> 1) * 64;
  const int ln = lane & 15;
  const int q  = lane >> 4;

  f32x4 acc[AI][4];
#pragma unroll
  for (int i=0;i<AI;i++)
#pragma unroll
    for (int j=0;j<4;j++) acc[i][j] = (f32x4)0.f;

  const int ldKw = K >> 1;
  const int br = tid >> 1, bh = tid & 1;

  for (int kt = 0; kt < K/GBK; kt++){
    if (AM == 1){
      const int ar = tid >> 2, ah = tid & 3;
      const int row = (m0+ar)*4 + (kt>>3);
      const uint4* ap = (const uint4*)(Abf + (size_t)row*512 + (kt&7)*64 + ah*16);
      *((uint4*)&aL[ar*LSTR + ah*8    ]) = ap[0];
      *((uint4*)&aL[ar*LSTR + ah*8 + 4]) = ap[1];
    } else {
      const int ar = tid >> 1, ah = tid & 1;
      const int k0 = kt*GBK;
      const unsigned int* ub = ((k0 < 512) ? A1 : A2)
                               + (size_t)(m0+ar)*HW + ((k0 & 511) >> 1) + ah*16;
#pragma unroll
      for (int g=0; g<4; g++)
        *((uint4*)&aL[ar*LSTR + ah*16 + g*4]) = ((const uint4*)ub)[g];
    }
    {
      const unsigned int* bp = Bpk + (size_t)(n0+br)*ldKw + kt*32 + bh*16;
#pragma unroll
      for (int g=0; g<4; g++)
        *((uint4*)&bL[br*LSTR + bh*16 + g*4]) = ((const uint4*)bp)[g];
    }
    __syncthreads();
#pragma unroll
    for (int ks=0; ks<2; ks++){
      short8 af[AI], bf[4];
#pragma unroll
      for (int i=0;i<AI;i++){
        uint4 u = *(const uint4*)&aL[(wm + i*16 + ln)*LSTR + ks*16 + q*4];
        af[i] = *(const short8*)&u;
      }
#pragma unroll
      for (int j=0;j<4;j++){
        uint4 u = *(const uint4*)&bL[(wn + j*16 + ln)*LSTR + ks*16 + q*4];
        bf[j] = *(const short8*)&u;
      }
#pragma unroll
      for (int i=0;i<AI;i++)
#pragma unroll
        for (int j=0;j<4;j++)
          acc[i][j] = __builtin_amdgcn_mfma_f32_16x16x32_bf16(af[i], bf[j], acc[i][j], 0,0,0);
    }
    __syncthreads();
  }
#pragma unroll
  for (int i=0;i<AI;i++)
#pragma unroll
    for (int j=0;j<4;j++){
      int n = n0 + wn + j*16 + ln;
      float bs = (n < 1536) ? biasF[n] : biasB[n-1536];
#pragma unroll
      for (int r=0;r<4;r++){
        int m = m0 + wm + i*16 + q*4 + r;
        C[(size_t)m*ldc + n] = acc[i][j][r] + bs;
      }
    }
}

// ---------------------------------------------------------------------------
// scan4 (R12): exchange-free chunk-per-block GRU scan.
// Grid 128 x 1024thr. dir = bid&1, chunk = bid>>1 (CLEN=32, 64 chunks/dir).
// Thread: c = tid>>1 (column 0..511), half = tid&1 (rows half*256..+255).
// Weights: wv[96] uint4 = 384 packed-f16-row-pairs = this thread's
//   3 gate-columns (c, c+512, c+1024) x 256 rows. Layout streamed
//   [(g*32+kk4)*1024 + tid] (uint4), fully coalesced.
// Step: [gi load (even)] [dot: 64 uint2 LDS reads + 384 dot2]
//   [shfl_xor(1) merge] [even: GRU tail -> hS[p^1][c] (f16) + hb (bf16)]
//   [1 barrier]. No global sync of any kind.
// ---------------------------------------------------------------------------
__global__ __launch_bounds__(1024, 4)
void scan4_kernel(const float* __restrict__ gi,
                  const uint4* __restrict__ whF, const uint4* __restrict__ whB,
                  const float* __restrict__ bhnF, const float* __restrict__ bhnB,
                  unsigned short* __restrict__ hbF, unsigned short* __restrict__ hbB)
{
  const int bid = blockIdx.x;
  const int dir = bid & 1;
  const int chunk = bid >> 1;
  const int tid = threadIdx.x;
  const int c = tid >> 1;
  const int half = tid & 1;

  const float* gi_d = gi + dir*1536;
  const uint4* wq = dir ? whB : whF;
  const float* bhn = dir ? bhnB : bhnF;
  unsigned short* hb = dir ? hbB : hbF;

  // ---- full weight residency: 96 uint4 = 384 VGPRs
  uint4 wv[96];
#pragma unroll
  for (int u = 0; u < 96; u++)
    wv[u] = wq[(size_t)u*1024 + tid];

  __shared__ unsigned short hS[2][512];   // f16 h state, index = row
  if (tid < 512){ hS[0][tid] = 0; hS[1][tid] = 0; }
  __syncthreads();

  const float bh = (half == 0) ? bhn[c] : 0.f;
  float hp = 0.f;
  const int base = chunk*CLEN;

  for (int idx = 0; idx < NSTP; idx++){
    const int p = idx & 1;
    int t = dir ? (base + CLEN-1 + WARM - idx) : (base - WARM + idx);
    const bool valid = (t >= 0) && (t < T_SEQ);
    int tc = t < 0 ? 0 : (t > T_SEQ-1 ? T_SEQ-1 : t);
    float gr = 0.f, gz = 0.f, gn = 0.f;
    if (half == 0){
      const float* gbp = gi_d + (size_t)tc*GS + c;
      gr = gbp[0]; gz = gbp[512]; gn = gbp[1024];
    }

    // ---- dot: rows half*256..+255 against 3 gate columns
    const uint2* hrow = (const uint2*)&hS[p][half*256];
    float a0 = 0.f, a1 = 0.f, a2 = 0.f;
#pragma unroll
    for (int k4 = 0; k4 < 32; k4++){
      uint2 hv0 = hrow[2*k4], hv1 = hrow[2*k4+1];
      uint4 w0 = wv[k4], w1 = wv[32+k4], w2 = wv[64+k4];
      a0 = fdot2f(w0.x, hv0.x, a0); a1 = fdot2f(w1.x, hv0.x, a1); a2 = fdot2f(w2.x, hv0.x, a2);
      a0 = fdot2f(w0.y, hv0.y, a0); a1 = fdot2f(w1.y, hv0.y, a1); a2 = fdot2f(w2.y, hv0.y, a2);
      a0 = fdot2f(w0.z, hv1.x, a0); a1 = fdot2f(w1.z, hv1.x, a1); a2 = fdot2f(w2.z, hv1.x, a2);
      a0 = fdot2f(w0.w, hv1.y, a0); a1 = fdot2f(w1.w, hv1.y, a1); a2 = fdot2f(w2.w, hv1.y, a2);
    }
    // merge the two row-halves (lanes 2c / 2c+1)
    float s0 = a0 + __shfl_xor(a0, 1, 64);
    float s1 = a1 + __shfl_xor(a1, 1, 64);
    float s2 = a2 + __shfl_xor(a2, 1, 64);

    if (half == 0){
      float r = __fdividef(1.f, 1.f + __expf(-(gr + s0)));
      float z = __fdividef(1.f, 1.f + __expf(-(gz + s1)));
      float e = __expf(2.f*(gn + r*(s2 + bh)));
      float n = 1.f - __fdividef(2.f, e + 1.f);
      float h = (1.f - z)*n + z*hp;
      h = valid ? h : 0.f;
      hp = h;
      _Float16 hf = (_Float16)h;
      hS[p^1][c] = __builtin_bit_cast(unsigned short, hf);
      if (idx >= WARM)
        hb[(size_t)t*512 + c] = (unsigned short)(pack_bf16(h, h) & 0xFFFFu);
    }
    __syncthreads();
  }
}

// ---------------------------------------------------------------------------
// Decoder: logits = [hf|hb](packed bf16) @ Wdec + bdec, row log_softmax.
// ---------------------------------------------------------------------------
__global__ __launch_bounds__(64)
void decoder_kernel(const unsigned int* __restrict__ hf, const unsigned int* __restrict__ hbk,
                    const float* __restrict__ Wd, const float* __restrict__ bd,
                    float* __restrict__ out)
{
  const int t = blockIdx.x;
  const int lane = threadIdx.x;
  __shared__ float y[1024];
  for (int i = lane; i < HW; i += 64){
    unsigned int uf = hf [(size_t)t*HW + i];
    unsigned int ub = hbk[(size_t)t*HW + i];
    y[2*i]       = bf2f(uf & 0xFFFFu); y[2*i+1]       = bf2f(uf >> 16);
    y[512 + 2*i] = bf2f(ub & 0xFFFFu); y[512 + 2*i+1] = bf2f(ub >> 16);
  }
  __syncthreads();
  float v = -1e30f;
  if (lane < 41){
    float acc = bd[lane];
    for (int k=0;k<1024;k++) acc += y[k] * Wd[(size_t)k*41 + lane];
    v = acc;
  }
  float m = v;
#pragma unroll
  for (int off=32; off; off>>=1) m = fmaxf(m, __shfl_xor(m, off, 64));
  float e = (lane < 41) ? __expf(v - m) : 0.f;
  float ssum = e;
#pragma unroll
  for (int off=32; off; off>>=1) ssum += __shfl_xor(ssum, off, 64);
  if (lane < 41) out[(size_t)t*41 + lane] = (v - m) - __logf(ssum);
}

// ---------------------------------------------------------------------------
// Prep kernels
// ---------------------------------------------------------------------------
__global__ void zero_u_kernel(unsigned int* p, int n){
  int i = blockIdx.x*blockDim.x + threadIdx.x;
  if (i < n) p[i] = 0u;
}
// day weights: packed word[n][k2] = pack(dayW[d][n][2k2], dayW[d][n][2k2+1])
__global__ void daysel_kernel(const float* __restrict__ dw, const float* __restrict__ db,
                              const int* __restrict__ didx, unsigned int* __restrict__ wtpk,
                              float* __restrict__ bsel){
  int d = *didx;
  int i = blockIdx.x*256 + threadIdx.x;
  if (i < 512*256){
    int n = i >> 8, k2 = i & 255;
    const float* s = dw + (size_t)d*262144 + (size_t)n*512 + 2*k2;
    wtpk[i] = pack_bf16(s[0], s[1]);
  }
  if (i < 512) bsel[i] = db[(size_t)d*512 + i];
}
// Transpose-pack fp32 B [K][ldb] column slice -> pair-words dst[n][K/2].
__global__ __launch_bounds__(256)
void packB_kernel(const float* __restrict__ src, int ldb,
                  unsigned int* __restrict__ dst, int K)
{
  __shared__ float tile[64][65];
  const int k0 = blockIdx.x * 64;
  const int n0 = blockIdx.y * 64;
  const int tid = threadIdx.x;
#pragma unroll
  for (int g=0; g<16; g++){
    int idx = g*256 + tid;
    int kr = idx >> 6, nc = idx & 63;
    tile[kr][nc] = src[(size_t)(k0+kr)*ldb + n0 + nc];
  }
  __syncthreads();
  const int ldKw = K >> 1;
#pragma unroll
  for (int g=0; g<8; g++){
    int wi = g*256 + tid;
    int nl = wi >> 5, k2 = wi & 31;
    dst[(size_t)(n0+nl)*ldKw + (k0>>1) + k2] = pack_bf16(tile[2*k2][nl], tile[2*k2+1][nl]);
  }
}
// Wh pack for scan4: word i (per matrix): kq=i&3; t=(i>>2)&1023;
// kk4=(i>>12)&31; g=i>>17 (0..2). c=t>>1, half=t&1, kk=4kk4+kq,
// r0 = half*256+2kk, col = g*512+c. value = f16x2(W[r0][col], W[r0+1][col]).
struct WhPtrs { const float* p[10]; };
__global__ void whpack3_kernel(WhPtrs wps, unsigned int* __restrict__ dst){
  long i = (long)blockIdx.x*256 + threadIdx.x;
  if (i >= 10L*393216L) return;
  int ld = (int)(i / 393216);
  int o  = (int)(i % 393216);
  int kq  = o & 3;
  int t   = (o >> 2) & 1023;
  int kk4 = (o >> 12) & 31;
  int g   = o >> 17;
  int c = t >> 1, half = t & 1;
  int kk = kk4*4 + kq;
  int r0 = half*256 + 2*kk;
  int col = g*512 + c;
  const float* W = wps.p[ld];
  _Float16 x0 = (_Float16)W[(size_t)r0*G3 + col];
  _Float16 x1 = (_Float16)W[(size_t)(r0+1)*G3 + col];
  unsigned int b0 = __builtin_bit_cast(unsigned short, x0);
  unsigned int b1 = __builtin_bit_cast(unsigned short, x1);
  dst[i] = (b1 << 16) | b0;
}

// ---------------------------------------------------------------------------
extern "C" void kernel_launch(void* const* d_in, const int* in_sizes, int n_in,
                              void* d_out, int out_size, void* d_ws, size_t ws_size,
                              hipStream_t stream)
{
  const float* x     = (const float*)d_in[0];
  const int*   didx  = (const int*)  d_in[1];
  const float* dayW  = (const float*)d_in[2];
  const float* dayB  = (const float*)d_in[3];
  const float* Wi0f  = (const float*)d_in[4];
  const float* bi0f  = (const float*)d_in[5];
  const float* Wh0f  = (const float*)d_in[6];
  const float* bhn0f = (const float*)d_in[7];
  const float* Wi0b  = (const float*)d_in[8];
  const float* bi0b  = (const float*)d_in[9];
  const float* Wh0b  = (const float*)d_in[10];
  const float* bhn0b = (const float*)d_in[11];
  const float* WiRf  = (const float*)d_in[12];
  const float* biRf  = (const float*)d_in[13];
  const float* WhRf  = (const float*)d_in[14];
  const float* bhnRf = (const float*)d_in[15];
  const float* WiRb  = (const float*)d_in[16];
  const float* biRb  = (const float*)d_in[17];
  const float* WhRb  = (const float*)d_in[18];
  const float* bhnRb = (const float*)d_in[19];
  const float* Wdec  = (const float*)d_in[20];
  const float* bdec  = (const float*)d_in[21];
  float* out = (float*)d_out;

  char* ws = (char*)d_ws;
  size_t off = 0;
  unsigned int* hbuf[5][2];
  for (int l=0;l<5;l++) for (int d=0;d<2;d++){
    hbuf[l][d] = (unsigned int*)(ws+off); off += (size_t)T_SEQ*HW*4;
  }
  float* gi   = (float*)(ws+off); off += (size_t)T_SEQ*GS*4;             // 25.2 MB
  unsigned short* hpadb = (unsigned short*)(ws+off); off += ((size_t)8223*512*2 + 255) & ~255ull;
  unsigned int* wtpk = (unsigned int*)(ws+off); off += (size_t)512*256*4;
  float* bsel = (float*)(ws+off); off += 2048;
  unsigned int* whq = (unsigned int*)(ws+off); off += (size_t)10*393216*4;   // 15.7 MB
  unsigned int* bpk0 = (unsigned int*)(ws+off); off += (size_t)3072*8192*4;   // 100.7 MB
  unsigned int* bpkR = (unsigned int*)(ws+off); off += (size_t)4*3072*512*4;  // 25.2 MB
  // total ~195 MB

  // --- prep
  hipLaunchKernelGGL(zero_u_kernel, dim3((7936+255)/256), dim3(256), 0, stream,
                     (unsigned int*)hpadb, 7936);  // rows 0..30 bf16 zeros
  hipLaunchKernelGGL(daysel_kernel, dim3(512), dim3(256), 0, stream,
                     dayW, dayB, didx, wtpk, bsel);
  WhPtrs wps;
  wps.p[0] = Wh0f; wps.p[1] = Wh0b;
  for (int l=0;l<4;l++){
    wps.p[2+2*l] = WhRf + (size_t)l*512*1536;
    wps.p[3+2*l] = WhRb + (size_t)l*512*1536;
  }
  hipLaunchKernelGGL(whpack3_kernel, dim3((10*393216+255)/256), dim3(256), 0, stream,
                     wps, whq);

  // --- pre-pack input-gate weights to bf16 pair-words [n][K/2], fwd|bwd fused
  hipLaunchKernelGGL(packB_kernel, dim3(256,24), dim3(256), 0, stream,
                     Wi0f, G3, bpk0, 16384);
  hipLaunchKernelGGL(packB_kernel, dim3(256,24), dim3(256), 0, stream,
                     Wi0b, G3, bpk0 + (size_t)1536*8192, 16384);
  for (int l=0;l<4;l++){
    unsigned int* d = bpkR + (size_t)l*3072*512;
    hipLaunchKernelGGL(packB_kernel, dim3(16,24), dim3(256), 0, stream,
                       WiRf + (size_t)l*1024*1536, G3, d, 1024);
    hipLaunchKernelGGL(packB_kernel, dim3(16,24), dim3(256), 0, stream,
                       WiRb + (size_t)l*1024*1536, G3, d + (size_t)1536*512, 1024);
  }

  // --- day transform + softsign -> bf16 hpadb rows 31..8222
  hipLaunchKernelGGL(day_gemm, dim3(64,4), dim3(256), 0, stream,
                     x, wtpk, bsel, hpadb);

  // --- layer 0 input gates: fused fwd+bwd, frame-gather bf16 A, 768 blocks
  hipLaunchKernelGGL(HIP_KERNEL_NAME(gemm_bt<64,1>), dim3(32,24), dim3(256), 0, stream,
                     hpadb, (const unsigned int*)nullptr, (const unsigned int*)nullptr,
                     bpk0, bi0f, bi0b, gi, 16384, GS);
  hipLaunchKernelGGL(scan4_kernel, dim3(128), dim3(1024), 0, stream,
                     gi, (const uint4*)whq, (const uint4*)(whq + (size_t)393216),
                     bhn0f, bhn0b,
                     (unsigned short*)hbuf[0][0], (unsigned short*)hbuf[0][1]);

  // --- layers 1..4: fused fwd+bwd GEMM (N=3072), then scan
  for (int l=1;l<5;l++){
    hipLaunchKernelGGL(HIP_KERNEL_NAME(gemm_bt<128,2>), dim3(16,24), dim3(256), 0, stream,
                       (const unsigned short*)nullptr, hbuf[l-1][0], hbuf[l-1][1],
                       bpkR + (size_t)(l-1)*3072*512,
                       biRf + (l-1)*1536, biRb + (l-1)*1536, gi, 1024, GS);
    hipLaunchKernelGGL(scan4_kernel, dim3(128), dim3(1024), 0, stream,
                       gi, (const uint4*)(whq + (size_t)(2*l)*393216),
                       (const uint4*)(whq + (size_t)(2*l+1)*393216),
                       bhnRf + (l-1)*512, bhnRb + (l-1)*512,
                       (unsigned short*)hbuf[l][0], (unsigned short*)hbuf[l][1]);
  }

  // --- decoder + log_softmax
  hipLaunchKernelGGL(decoder_kernel, dim3(2048), dim3(64), 0, stream,
                     hbuf[4][0], hbuf[4][1], Wdec, bdec, out);
}

// Round 9
// 2953.091 us; speedup vs baseline: 6.2837x; 6.2837x over previous
//
#include <hip/hip_runtime.h>
#include <stdint.h>

// ---------------------------------------------------------------------------
// RNN speech decoder. R13:
//  * R12 post-mortem: 1024-thread 384-VGPR weight residency spilled (VGPR=64,
//    FETCH 7.1GB) - same as R6. Exchange-free branch closed.
//  * R13 = R9 (best MFMA scan, proven) with ONE fix: the poll retry loop
//    reloads ALL 7 partners into fresh temps then merges, instead of
//    load-and-immediately-check per partner. R9's pattern serialized up to
//    7 L3 round trips (~6300cy) per step; batched retry = ~1 round trip
//    per round. Also: exchange store issued BEFORE hb store (earliest
//    visibility).
//  * Everything else byte-identical to R9 (scan2 MFMA core, poison
//    protocol, GEMM stack, decoder, prep).
// ---------------------------------------------------------------------------

#define T_SEQ 2048
#define G3    1536
#define GS    3072   // fused gate width (fwd | bwd)
#define HW    256    // packed bf16 words per h vector
#define CLEN  64
#define WARM  64
#define NCH   32     // chunks per dir
#define NST   128    // steps per scan (CLEN+WARM)

typedef __attribute__((ext_vector_type(8))) short short8;
typedef __attribute__((ext_vector_type(4))) float f32x4;

__device__ inline unsigned int pack_bf16(float a, float b){
  unsigned int ua = __float_as_uint(a); ua = (ua + 0x7FFFu + ((ua>>16)&1u)) >> 16;
  unsigned int ub = __float_as_uint(b); ub = (ub + 0x7FFFu + ((ub>>16)&1u)) >> 16;
  return (ub<<16) | (ua & 0xFFFFu);
}
__device__ inline float bf2f(unsigned int h){ return __uint_as_float(h<<16); }

#define GBN 128
#define GBK 64
#define LSTR 36

// ---------------------------------------------------------------------------
// Day GEMM: C = softsign(x @ dayWT + bsel) -> bf16 hpadb rows 31..8222.
// ---------------------------------------------------------------------------
__global__ __launch_bounds__(256)
void day_gemm(const float* __restrict__ A, const unsigned int* __restrict__ Bpk,
              const float* __restrict__ bias, unsigned short* __restrict__ Cb)
{
  __shared__ __align__(16) unsigned int aL[128*LSTR];
  __shared__ __align__(16) unsigned int bL[GBN*LSTR];
  const int tid = threadIdx.x;
  const int m0 = blockIdx.x * 128;
  const int n0 = blockIdx.y * GBN;
  const int lane = tid & 63;
  const int w = tid >> 6;
  const int wm = (w & 1) * 64;
  const int wn = (w >> 1) * 64;
  const int ln = lane & 15;
  const int q  = lane >> 4;
  const int K = 512;

  f32x4 acc[4][4];
#pragma unroll
  for (int i=0;i<4;i++)
#pragma unroll
    for (int j=0;j<4;j++) acc[i][j] = (f32x4)0.f;

  const int ar = tid >> 1, ah = tid & 1;
  const int br = tid >> 1, bh = tid & 1;

  for (int kt = 0; kt < K/GBK; kt++){
    {
      const float* ap = A + (size_t)(m0+ar)*K + kt*GBK + ah*32;
      float4 av[8];
#pragma unroll
      for (int g=0; g<8; g++) av[g] = ((const float4*)ap)[g];
#pragma unroll
      for (int g=0; g<8; g++){
        aL[ar*LSTR + ah*16 + g*2    ] = pack_bf16(av[g].x, av[g].y);
        aL[ar*LSTR + ah*16 + g*2 + 1] = pack_bf16(av[g].z, av[g].w);
      }
    }
    {
      const unsigned int* bp = Bpk + (size_t)(n0+br)*(K>>1) + kt*32 + bh*16;
#pragma unroll
      for (int g=0; g<4; g++)
        *((uint4*)&bL[br*LSTR + bh*16 + g*4]) = ((const uint4*)bp)[g];
    }
    __syncthreads();
#pragma unroll
    for (int ks=0; ks<2; ks++){
      short8 af[4], bf[4];
#pragma unroll
      for (int i=0;i<4;i++){
        uint4 u = *(const uint4*)&aL[(wm + i*16 + ln)*LSTR + ks*16 + q*4];
        af[i] = *(const short8*)&u;
      }
#pragma unroll
      for (int j=0;j<4;j++){
        uint4 u = *(const uint4*)&bL[(wn + j*16 + ln)*LSTR + ks*16 + q*4];
        bf[j] = *(const short8*)&u;
      }
#pragma unroll
      for (int i=0;i<4;i++)
#pragma unroll
        for (int j=0;j<4;j++)
          acc[i][j] = __builtin_amdgcn_mfma_f32_16x16x32_bf16(af[i], bf[j], acc[i][j], 0,0,0);
    }
    __syncthreads();
  }
#pragma unroll
  for (int i=0;i<4;i++)
#pragma unroll
    for (int j=0;j<4;j++){
      int n = n0 + wn + j*16 + ln;
      float bs = bias[n];
#pragma unroll
      for (int r=0;r<4;r++){
        int m = m0 + wm + i*16 + q*4 + r;
        float v = acc[i][j][r] + bs;
        v = v / (1.f + fabsf(v));
        Cb[(size_t)(m+31)*512 + n] = (unsigned short)(pack_bf16(v, v) & 0xFFFFu);
      }
    }
}

// ---------------------------------------------------------------------------
// Input-gate GEMM, bf16 A (unchanged).
// ---------------------------------------------------------------------------
template<int BM, int AM>
__global__ __launch_bounds__(256)
void gemm_bt(const unsigned short* __restrict__ Abf,
             const unsigned int* __restrict__ A1, const unsigned int* __restrict__ A2,
             const unsigned int* __restrict__ Bpk,
             const float* __restrict__ biasF, const float* __restrict__ biasB,
             float* __restrict__ C, int K, int ldc)
{
  constexpr int AI = BM/32;
  __shared__ __align__(16) unsigned int aL[BM*LSTR];
  __shared__ __align__(16) unsigned int bL[GBN*LSTR];
  const int tid = threadIdx.x;
  const int m0 = blockIdx.x * BM;
  const int n0 = blockIdx.y * GBN;
  const int lane = tid & 63;
  const int w = tid >> 6;
  const int wm = (w & 1) * (BM/2);
  const int wn = (w >> 1) * 64;
  const int ln = lane & 15;
  const int q  = lane >> 4;

  f32x4 acc[AI][4];
#pragma unroll
  for (int i=0;i<AI;i++)
#pragma unroll
    for (int j=0;j<4;j++) acc[i][j] = (f32x4)0.f;

  const int ldKw = K >> 1;
  const int br = tid >> 1, bh = tid & 1;

  for (int kt = 0; kt < K/GBK; kt++){
    if (AM == 1){
      const int ar = tid >> 2, ah = tid & 3;
      const int row = (m0+ar)*4 + (kt>>3);
      const uint4* ap = (const uint4*)(Abf + (size_t)row*512 + (kt&7)*64 + ah*16);
      *((uint4*)&aL[ar*LSTR + ah*8    ]) = ap[0];
      *((uint4*)&aL[ar*LSTR + ah*8 + 4]) = ap[1];
    } else {
      const int ar = tid >> 1, ah = tid & 1;
      const int k0 = kt*GBK;
      const unsigned int* ub = ((k0 < 512) ? A1 : A2)
                               + (size_t)(m0+ar)*HW + ((k0 & 511) >> 1) + ah*16;
#pragma unroll
      for (int g=0; g<4; g++)
        *((uint4*)&aL[ar*LSTR + ah*16 + g*4]) = ((const uint4*)ub)[g];
    }
    {
      const unsigned int* bp = Bpk + (size_t)(n0+br)*ldKw + kt*32 + bh*16;
#pragma unroll
      for (int g=0; g<4; g++)
        *((uint4*)&bL[br*LSTR + bh*16 + g*4]) = ((const uint4*)bp)[g];
    }
    __syncthreads();
#pragma unroll
    for (int ks=0; ks<2; ks++){
      short8 af[AI], bf[4];
#pragma unroll
      for (int i=0;i<AI;i++){
        uint4 u = *(const uint4*)&aL[(wm + i*16 + ln)*LSTR + ks*16 + q*4];
        af[i] = *(const short8*)&u;
      }
#pragma unroll
      for (int j=0;j<4;j++){
        uint4 u = *(const uint4*)&bL[(wn + j*16 + ln)*LSTR + ks*16 + q*4];
        bf[j] = *(const short8*)&u;
      }
#pragma unroll
      for (int i=0;i<AI;i++)
#pragma unroll
        for (int j=0;j<4;j++)
          acc[i][j] = __builtin_amdgcn_mfma_f32_16x16x32_bf16(af[i], bf[j], acc[i][j], 0,0,0);
    }
    __syncthreads();
  }
#pragma unroll
  for (int i=0;i<AI;i++)
#pragma unroll
    for (int j=0;j<4;j++){
      int n = n0 + wn + j*16 + ln;
      float bs = (n < 1536) ? biasF[n] : biasB[n-1536];
#pragma unroll
      for (int r=0;r<4;r++){
        int m = m0 + wm + i*16 + q*4 + r;
        C[(size_t)m*ldc + n] = acc[i][j][r] + bs;
      }
    }
}

// ---------------------------------------------------------------------------
// scan2 (R13): M-batched MFMA GRU scan, poison-payload sync, batched retry.
// Grid 16 x 512thr. dir = bid>>3, j = bid&7. Per step:
//   [gi prefetch] [poll 7 partner ull: initial batch + BATCHED retry rounds
//   (7 loads in flight, one wait, then merge) -> hA[p]] [B1]
//   [MFMA K-split, gL write] [B2] [activation; exch publish FIRST, then hb].
// ---------------------------------------------------------------------------
__global__ __launch_bounds__(512)
void scan2_kernel(const float* __restrict__ gi,
                  const uint4* __restrict__ wqF, const uint4* __restrict__ wqB,
                  const float* __restrict__ bhnF, const float* __restrict__ bhnB,
                  unsigned int* __restrict__ hbF, unsigned int* __restrict__ hbB,
                  unsigned long long* __restrict__ exch)
{
  const int bid = blockIdx.x;
  const int dir = bid >> 3;
  const int j   = bid & 7;
  const int tid = threadIdx.x;
  const int w    = tid >> 6;
  const int lane = tid & 63;
  const int ln = lane & 15, q = lane >> 4;
  const int kt = w >> 2, wn = w & 3;
  const unsigned long long POI = 0xAAAAAAAAAAAAAAAAull;

  const float* gi_d = gi + dir*1536;
  const uint4* wq = dir ? wqB : wqF;
  const float* bhn = dir ? bhnB : bhnF;
  unsigned int* hb = dir ? hbB : hbF;
  unsigned long long* exd = exch + (size_t)dir*8*NST*512;

  // ---- weights: 24 frags/lane (3 nt x 8 kk-local)
  short8 w8[3][8];
  {
    const uint4* wb = wq + (size_t)j*12*16*64;
#pragma unroll
    for (int nt=0; nt<3; nt++)
#pragma unroll
      for (int kkl=0; kkl<8; kkl++){
        uint4 u = wb[(size_t)(((wn*3+nt)*16) + (kt*8+kkl))*64 + lane];
        w8[nt][kkl] = *(const short8*)&u;
      }
  }

  __shared__ __align__(16) unsigned short hA[2][NCH][512];
  __shared__ __align__(16) float gL[2][NCH][196];

  const int m  = tid >> 4;   // chunk
  const int cp = tid & 15;
  const int c0 = 4*cp;
  float4 bh4 = *(const float4*)&bhn[j*64 + c0];
  float hp0=0.f, hp1=0.f, hp2=0.f, hp3=0.f;

  {
    uint4 zz; zz.x=0u; zz.y=0u; zz.z=0u; zz.w=0u;
    uint4* zp = (uint4*)&hA[0][0][0];
    for (int i2 = tid; i2 < 2048; i2 += 512) zp[i2] = zz;
  }
  __syncthreads();

  for (int idx = 0; idx < NST; idx++){
    const int p = idx & 1;
    // gi prefetch (validity-clamped address)
    int t = dir ? (64*m + 127 - idx) : (64*m - 64 + idx);
    const bool valid = (t >= 0) && (t < T_SEQ);
    int tc = t < 0 ? 0 : (t > T_SEQ-1 ? T_SEQ-1 : t);
    const float* gb = gi_d + (size_t)tc*GS + j*64 + c0;
    float4 g_r = *(const float4*)(gb);
    float4 g_z = *(const float4*)(gb + 512);
    float4 g_n = *(const float4*)(gb + 1024);

    if (idx > 0){
      const unsigned long long* ap[7];
#pragma unroll
      for (int rb = 0; rb < 7; rb++){
        int jr = (j + 1 + rb) & 7;
        ap[rb] = &exd[((size_t)jr*NST + (idx-1))*512 + tid];
      }
      // initial batch: 7 loads in flight
      unsigned long long v[7];
#pragma unroll
      for (int rb = 0; rb < 7; rb++)
        v[rb] = __hip_atomic_load(ap[rb], __ATOMIC_RELAXED, __HIP_MEMORY_SCOPE_AGENT);
      // batched retry: each round issues ALL 7 loads (no use in between ->
      // they stay in flight together), then merges into the miss slots.
      for (;;){
        bool bad = false;
#pragma unroll
        for (int rb = 0; rb < 7; rb++)
          if (v[rb] == POI) bad = true;
        if (!bad) break;
        unsigned long long nv[7];
#pragma unroll
        for (int rb = 0; rb < 7; rb++)
          nv[rb] = __hip_atomic_load(ap[rb], __ATOMIC_RELAXED, __HIP_MEMORY_SCOPE_AGENT);
#pragma unroll
        for (int rb = 0; rb < 7; rb++)
          if (v[rb] == POI) v[rb] = nv[rb];
      }
#pragma unroll
      for (int rb = 0; rb < 7; rb++){
        int jr = (j + 1 + rb) & 7;
        int uo = (m*512 + jr*64 + c0) ^ ((m&7)<<3);
        ((unsigned long long*)&hA[p][0][0])[uo>>2] = v[rb];
      }
    }
    __syncthreads();                       // B1

    // ---- MFMA: H[32x512] @ WhT-slice, K-half kt
    f32x4 acA[3], acB[3];
#pragma unroll
    for (int nt=0; nt<3; nt++){ acA[nt] = (f32x4)0.f; acB[nt] = (f32x4)0.f; }
    const unsigned short* hbp = &hA[p][0][0];
#pragma unroll
    for (int kkl=0; kkl<8; kkl++){
      int kb = (kt*8 + kkl)*32 + q*8;
      int ua = (ln*512 + kb) ^ ((ln&7)<<3);
      int ub = ((16+ln)*512 + kb) ^ (((16+ln)&7)<<3);
      short8 af0 = *(const short8*)&hbp[ua];
      short8 af1 = *(const short8*)&hbp[ub];
#pragma unroll
      for (int nt=0; nt<3; nt++){
        acA[nt] = __builtin_amdgcn_mfma_f32_16x16x32_bf16(af0, w8[nt][kkl], acA[nt], 0,0,0);
        acB[nt] = __builtin_amdgcn_mfma_f32_16x16x32_bf16(af1, w8[nt][kkl], acB[nt], 0,0,0);
      }
    }
#pragma unroll
    for (int nt=0; nt<3; nt++){
      int ncol = (wn*3+nt)*16 + ln;
      float* gw = &gL[kt][0][0];
#pragma unroll
      for (int r=0; r<4; r++){
        gw[(4*q + r)*196 + ncol]      = acA[nt][r];
        gw[(16 + 4*q + r)*196 + ncol] = acB[nt][r];
      }
    }
    __syncthreads();                       // B2

    // ---- activation: thread = (chunk m, cols c0..c0+3)
    const float* g0 = &gL[0][m][0];
    const float* g1 = &gL[1][m][0];
    float4 xr0 = *(const float4*)&g0[c0],     xr1 = *(const float4*)&g1[c0];
    float4 xz0 = *(const float4*)&g0[64+c0],  xz1 = *(const float4*)&g1[64+c0];
    float4 xn0 = *(const float4*)&g0[128+c0], xn1 = *(const float4*)&g1[128+c0];

    float h0,h1,h2,h3;
    {
      float ar = xr0.x + xr1.x, az = xz0.x + xz1.x, an = xn0.x + xn1.x;
      float r = __fdividef(1.f, 1.f + __expf(-(g_r.x + ar)));
      float z = __fdividef(1.f, 1.f + __expf(-(g_z.x + az)));
      float e = __expf(2.f*(g_n.x + r*(an + bh4.x)));
      float n = 1.f - __fdividef(2.f, e + 1.f);
      h0 = (1.f - z)*n + z*hp0; h0 = valid ? h0 : 0.f; hp0 = h0;
    }
    {
      float ar = xr0.y + xr1.y, az = xz0.y + xz1.y, an = xn0.y + xn1.y;
      float r = __fdividef(1.f, 1.f + __expf(-(g_r.y + ar)));
      float z = __fdividef(1.f, 1.f + __expf(-(g_z.y + az)));
      float e = __expf(2.f*(g_n.y + r*(an + bh4.y)));
      float n = 1.f - __fdividef(2.f, e + 1.f);
      h1 = (1.f - z)*n + z*hp1; h1 = valid ? h1 : 0.f; hp1 = h1;
    }
    {
      float ar = xr0.z + xr1.z, az = xz0.z + xz1.z, an = xn0.z + xn1.z;
      float r = __fdividef(1.f, 1.f + __expf(-(g_r.z + ar)));
      float z = __fdividef(1.f, 1.f + __expf(-(g_z.z + az)));
      float e = __expf(2.f*(g_n.z + r*(an + bh4.z)));
      float n = 1.f - __fdividef(2.f, e + 1.f);
      h2 = (1.f - z)*n + z*hp2; h2 = valid ? h2 : 0.f; hp2 = h2;
    }
    {
      float ar = xr0.w + xr1.w, az = xz0.w + xz1.w, an = xn0.w + xn1.w;
      float r = __fdividef(1.f, 1.f + __expf(-(g_r.w + ar)));
      float z = __fdividef(1.f, 1.f + __expf(-(g_z.w + az)));
      float e = __expf(2.f*(g_n.w + r*(an + bh4.w)));
      float n = 1.f - __fdividef(2.f, e + 1.f);
      h3 = (1.f - z)*n + z*hp3; h3 = valid ? h3 : 0.f; hp3 = h3;
    }

    unsigned int w0 = pack_bf16(h0,h1), w1 = pack_bf16(h2,h3);
    unsigned long long pv = ((unsigned long long)w1 << 32) | (unsigned long long)w0;
    if (pv == POI) pv ^= 1ull;             // poison collision: 1-ulp flip
    // publish FIRST (earliest L3 visibility), then local LDS + hb
    __hip_atomic_store(&exd[((size_t)j*NST + idx)*512 + tid], pv,
                       __ATOMIC_RELAXED, __HIP_MEMORY_SCOPE_AGENT);
    int uo = (m*512 + j*64 + c0) ^ ((m&7)<<3);
    ((unsigned long long*)&hA[p^1][0][0])[uo>>2] = pv;
    if (idx >= WARM)
      ((unsigned long long*)hb)[(size_t)t*128 + 16*j + cp] = pv;
    // no 3rd barrier: parity dbuf keeps LDS writes disjoint (see R9).
  }
}

// ---------------------------------------------------------------------------
// Decoder: logits = [hf|hb](packed bf16) @ Wdec + bdec, row log_softmax.
// ---------------------------------------------------------------------------
__global__ __launch_bounds__(64)
void decoder_kernel(const unsigned int* __restrict__ hf, const unsigned int* __restrict__ hbk,
                    const float* __restrict__ Wd, const float* __restrict__ bd,
                    float* __restrict__ out)
{
  const int t = blockIdx.x;
  const int lane = threadIdx.x;
  __shared__ float y[1024];
  for (int i = lane; i < HW; i += 64){
    unsigned int uf = hf [(size_t)t*HW + i];
    unsigned int ub = hbk[(size_t)t*HW + i];
    y[2*i]       = bf2f(uf & 0xFFFFu); y[2*i+1]       = bf2f(uf >> 16);
    y[512 + 2*i] = bf2f(ub & 0xFFFFu); y[512 + 2*i+1] = bf2f(ub >> 16);
  }
  __syncthreads();
  float v = -1e30f;
  if (lane < 41){
    float acc = bd[lane];
    for (int k=0;k<1024;k++) acc += y[k] * Wd[(size_t)k*41 + lane];
    v = acc;
  }
  float m = v;
#pragma unroll
  for (int off=32; off; off>>=1) m = fmaxf(m, __shfl_xor(m, off, 64));
  float e = (lane < 41) ? __expf(v - m) : 0.f;
  float ssum = e;
#pragma unroll
  for (int off=32; off; off>>=1) ssum += __shfl_xor(ssum, off, 64);
  if (lane < 41) out[(size_t)t*41 + lane] = (v - m) - __logf(ssum);
}

// ---------------------------------------------------------------------------
// Prep kernels
// ---------------------------------------------------------------------------
__global__ void poison_kernel(unsigned int* p, long n){
  long i = (long)blockIdx.x*blockDim.x + threadIdx.x;
  long st = (long)gridDim.x*blockDim.x;
  for (; i < n; i += st) p[i] = 0xAAAAAAAAu;
}
__global__ void zero_u_kernel(unsigned int* p, int n){
  int i = blockIdx.x*blockDim.x + threadIdx.x;
  if (i < n) p[i] = 0u;
}
// day weights: packed word[n][k2] = pack(dayW[d][n][2k2], dayW[d][n][2k2+1])
__global__ void daysel_kernel(const float* __restrict__ dw, const float* __restrict__ db,
                              const int* __restrict__ didx, unsigned int* __restrict__ wtpk,
                              float* __restrict__ bsel){
  int d = *didx;
  int i = blockIdx.x*256 + threadIdx.x;
  if (i < 512*256){
    int n = i >> 8, k2 = i & 255;
    const float* s = dw + (size_t)d*262144 + (size_t)n*512 + 2*k2;
    wtpk[i] = pack_bf16(s[0], s[1]);
  }
  if (i < 512) bsel[i] = db[(size_t)d*512 + i];
}
// Transpose-pack fp32 B [K][ldb] column slice -> pair-words dst[n][K/2].
__global__ __launch_bounds__(256)
void packB_kernel(const float* __restrict__ src, int ldb,
                  unsigned int* __restrict__ dst, int K)
{
  __shared__ float tile[64][65];
  const int k0 = blockIdx.x * 64;
  const int n0 = blockIdx.y * 64;
  const int tid = threadIdx.x;
#pragma unroll
  for (int g=0; g<16; g++){
    int idx = g*256 + tid;
    int kr = idx >> 6, nc = idx & 63;
    tile[kr][nc] = src[(size_t)(k0+kr)*ldb + n0 + nc];
  }
  __syncthreads();
  const int ldKw = K >> 1;
#pragma unroll
  for (int g=0; g<8; g++){
    int wi = g*256 + tid;
    int nl = wi >> 5, k2 = wi & 31;
    dst[(size_t)(n0+nl)*ldKw + (k0>>1) + k2] = pack_bf16(tile[2*k2][nl], tile[2*k2+1][nl]);
  }
}
// Wh frag-pack for scan2 (unchanged layout from R8).
struct WhPtrs { const float* p[10]; };
__global__ void whfrag_kernel(WhPtrs wps, uint4* __restrict__ dst){
  int i = blockIdx.x*256 + threadIdx.x;
  if (i >= 983040) return;
  int lane = i & 63;
  int r1 = i >> 6;
  int kk = r1 & 15;
  int r2 = r1 >> 4;
  int nt = r2 % 12;
  int r3 = r2 / 12;
  int j  = r3 & 7;
  int ld = r3 >> 3;
  int nl = nt*16 + (lane & 15);
  int sec = nl >> 6, off = nl & 63;
  int gcol = sec*512 + j*64 + off;
  int kb = kk*32 + (lane >> 4)*8;
  const float* W = wps.p[ld];
  unsigned int wd[4];
#pragma unroll
  for (int wq2=0; wq2<4; wq2++)
    wd[wq2] = pack_bf16(W[(size_t)(kb + 2*wq2)*G3 + gcol],
                        W[(size_t)(kb + 2*wq2 + 1)*G3 + gcol]);
  uint4 o; o.x = wd[0]; o.y = wd[1]; o.z = wd[2]; o.w = wd[3];
  dst[i] = o;
}

// ---------------------------------------------------------------------------
extern "C" void kernel_launch(void* const* d_in, const int* in_sizes, int n_in,
                              void* d_out, int out_size, void* d_ws, size_t ws_size,
                              hipStream_t stream)
{
  const float* x     = (const float*)d_in[0];
  const int*   didx  = (const int*)  d_in[1];
  const float* dayW  = (const float*)d_in[2];
  const float* dayB  = (const float*)d_in[3];
  const float* Wi0f  = (const float*)d_in[4];
  const float* bi0f  = (const float*)d_in[5];
  const float* Wh0f  = (const float*)d_in[6];
  const float* bhn0f = (const float*)d_in[7];
  const float* Wi0b  = (const float*)d_in[8];
  const float* bi0b  = (const float*)d_in[9];
  const float* Wh0b  = (const float*)d_in[10];
  const float* bhn0b = (const float*)d_in[11];
  const float* WiRf  = (const float*)d_in[12];
  const float* biRf  = (const float*)d_in[13];
  const float* WhRf  = (const float*)d_in[14];
  const float* bhnRf = (const float*)d_in[15];
  const float* WiRb  = (const float*)d_in[16];
  const float* biRb  = (const float*)d_in[17];
  const float* WhRb  = (const float*)d_in[18];
  const float* bhnRb = (const float*)d_in[19];
  const float* Wdec  = (const float*)d_in[20];
  const float* bdec  = (const float*)d_in[21];
  float* out = (float*)d_out;

  char* ws = (char*)d_ws;
  size_t off = 0;
  unsigned int* hbuf[5][2];
  for (int l=0;l<5;l++) for (int d=0;d<2;d++){
    hbuf[l][d] = (unsigned int*)(ws+off); off += (size_t)T_SEQ*HW*4;
  }
  float* gi   = (float*)(ws+off); off += (size_t)T_SEQ*GS*4;             // 25.2 MB
  unsigned short* hpadb = (unsigned short*)(ws+off); off += ((size_t)8223*512*2 + 255) & ~255ull;
  unsigned int* wtpk = (unsigned int*)(ws+off); off += (size_t)512*256*4;
  float* bsel = (float*)(ws+off); off += 2048;
  uint4* whq = (uint4*)(ws+off); off += (size_t)983040*16;               // 15.7 MB
  unsigned long long* exch = (unsigned long long*)(ws+off); off += (size_t)2*8*NST*512*8;  // 8.4 MB
  unsigned int* bpk0 = (unsigned int*)(ws+off); off += (size_t)3072*8192*4;   // 100.7 MB
  unsigned int* bpkR = (unsigned int*)(ws+off); off += (size_t)4*3072*512*4;  // 25.2 MB
  // total ~204 MB

  const long EXNW = (long)2*8*NST*512*2;   // exch in u32 words

  // --- prep
  hipLaunchKernelGGL(poison_kernel, dim3(1024), dim3(256), 0, stream,
                     (unsigned int*)exch, EXNW);
  hipLaunchKernelGGL(zero_u_kernel, dim3((7936+255)/256), dim3(256), 0, stream,
                     (unsigned int*)hpadb, 7936);  // rows 0..30 bf16 zeros
  hipLaunchKernelGGL(daysel_kernel, dim3(512), dim3(256), 0, stream,
                     dayW, dayB, didx, wtpk, bsel);
  WhPtrs wps;
  wps.p[0] = Wh0f; wps.p[1] = Wh0b;
  for (int l=0;l<4;l++){
    wps.p[2+2*l] = WhRf + (size_t)l*512*1536;
    wps.p[3+2*l] = WhRb + (size_t)l*512*1536;
  }
  hipLaunchKernelGGL(whfrag_kernel, dim3((983040+255)/256), dim3(256), 0, stream,
                     wps, whq);

  // --- pre-pack input-gate weights to bf16 pair-words [n][K/2], fwd|bwd fused
  hipLaunchKernelGGL(packB_kernel, dim3(256,24), dim3(256), 0, stream,
                     Wi0f, G3, bpk0, 16384);
  hipLaunchKernelGGL(packB_kernel, dim3(256,24), dim3(256), 0, stream,
                     Wi0b, G3, bpk0 + (size_t)1536*8192, 16384);
  for (int l=0;l<4;l++){
    unsigned int* d = bpkR + (size_t)l*3072*512;
    hipLaunchKernelGGL(packB_kernel, dim3(16,24), dim3(256), 0, stream,
                       WiRf + (size_t)l*1024*1536, G3, d, 1024);
    hipLaunchKernelGGL(packB_kernel, dim3(16,24), dim3(256), 0, stream,
                       WiRb + (size_t)l*1024*1536, G3, d + (size_t)1536*512, 1024);
  }

  // --- day transform + softsign -> bf16 hpadb rows 31..8222
  hipLaunchKernelGGL(day_gemm, dim3(64,4), dim3(256), 0, stream,
                     x, wtpk, bsel, hpadb);

  // --- layer 0 input gates: fused fwd+bwd, frame-gather bf16 A, 768 blocks
  hipLaunchKernelGGL(HIP_KERNEL_NAME(gemm_bt<64,1>), dim3(32,24), dim3(256), 0, stream,
                     hpadb, (const unsigned int*)nullptr, (const unsigned int*)nullptr,
                     bpk0, bi0f, bi0b, gi, 16384, GS);
  hipLaunchKernelGGL(scan2_kernel, dim3(16), dim3(512), 0, stream,
                     gi, whq, whq + (size_t)98304, bhn0f, bhn0b,
                     hbuf[0][0], hbuf[0][1], exch);

  // --- layers 1..4: fused fwd+bwd GEMM (N=3072), then scan
  for (int l=1;l<5;l++){
    hipLaunchKernelGGL(poison_kernel, dim3(1024), dim3(256), 0, stream,
                       (unsigned int*)exch, EXNW);
    hipLaunchKernelGGL(HIP_KERNEL_NAME(gemm_bt<128,2>), dim3(16,24), dim3(256), 0, stream,
                       (const unsigned short*)nullptr, hbuf[l-1][0], hbuf[l-1][1],
                       bpkR + (size_t)(l-1)*3072*512,
                       biRf + (l-1)*1536, biRb + (l-1)*1536, gi, 1024, GS);
    hipLaunchKernelGGL(scan2_kernel, dim3(16), dim3(512), 0, stream,
                       gi, whq + (size_t)(2*l)*98304, whq + (size_t)(2*l+1)*98304,
                       bhnRf + (l-1)*512, bhnRb + (l-1)*512,
                       hbuf[l][0], hbuf[l][1], exch);
  }

  // --- decoder + log_softmax
  hipLaunchKernelGGL(decoder_kernel, dim3(2048), dim3(64), 0, stream,
                     hbuf[4][0], hbuf[4][1], Wdec, bdec, out);
}